// Round 3
// baseline (600.635 us; speedup 1.0000x reference)
//
#include <hip/hip_runtime.h>

// DicepolyTopk: dice loss + mean of top-10% poly1-BCE values over N=16.7M fp32.
// R7: 3 dispatches: memset(262KB) -> pass1(+select1 in LAST block) ->
//     pass2(+sel2fin in LAST block).
// vs R6 (204.3us):
//  - last-block-done pattern (plain stores -> __threadfence -> atomicAdd(done);
//    last block __threadfence + reads). No spins -> no deadlock risk.
//  - select1 no longer replicated per pass2 block (was 1536 x 131KB = 201MB of
//    L2/L3 reads + a 16-barrier scan before every block's main loop).
//  - coalesced dual-stride loads: iteration loads p4[i] and p4[i+NT] (lane
//    stride 16B, dense) instead of p4[2i],p4[2i+1] (lane stride 32B, 2x
//    cacheline requests per instruction). 4 independent loads in flight.
//  - pass1: f32 accumulators (R0-proven exact), launch_bounds(256,8) -> 8
//    blocks/CU (LDS 17.5KB); pass2 stays (256,6) with 26KB LDS.

#define NBINS 4096
#define NREP1 8
#define NREP2 4
#define G1 2048
#define G2 1536
#define POLY_EPS 3.1f
#define LN2F 0.69314718056f

struct Ctl {
  unsigned int b1;  // L1 bucket containing the k-th largest value
  unsigned int r;   // k - count(strictly greater L1 buckets)
};

// bce in log2 domain: a2=log2(p), b2=log2(1-p); bce2 = -(b2 + t*(a2-b2))
// bce = bce2*ln2 ; pt = 2^(-bce2) ; poly1 = bce + (1-pt)*eps, clamped >= 0.
__device__ __forceinline__ float poly1_val(float p, float t) {
  float a2 = __builtin_amdgcn_logf(p);         // v_log_f32: log2(p)
  float b2 = __builtin_amdgcn_logf(1.0f - p);  // log2(1-p)
  float bce2 = -(b2 + t * (a2 - b2));
  float pt = __builtin_amdgcn_exp2f(-bce2);    // v_exp_f32: 2^(-bce2)
  float v = bce2 * LN2F + (1.0f - pt) * POLY_EPS;
  return v > 0.0f ? v : 0.0f;
}

// ---------------- pass 1: dice sums + L1 histogram (+select1 in last block) -
__global__ void __launch_bounds__(256, 8) pass1_kernel(
    const float* __restrict__ preds, const float* __restrict__ gts,
    long long n, unsigned int K, double* __restrict__ blockSums,
    unsigned int* __restrict__ hist1R, unsigned int* __restrict__ done1,
    Ctl* __restrict__ ctl) {
  __shared__ unsigned int h[NBINS];
  __shared__ double wred[4][3];
  __shared__ unsigned int chunk[256];
  __shared__ unsigned int lastFlag;
  const int t = threadIdx.x;
  for (int i = t; i < NBINS; i += 256) h[i] = 0u;
  __syncthreads();

  float fI = 0.f, fSp = 0.f, fSt = 0.f;
  const long long n4 = n >> 2;
  const float4* p4 = (const float4*)preds;
  const float4* t4 = (const float4*)gts;
  const long long NT = (long long)G1 * 256;
  const long long gtid = (long long)blockIdx.x * 256 + t;

#define PROC1(pp, tt)                                  \
  do {                                                 \
    float _p = (pp), _t = (tt);                        \
    fI += _p * _t;                                     \
    fSp += _p;                                         \
    fSt += _t;                                         \
    float _v = poly1_val(_p, _t);                      \
    atomicAdd(&h[__float_as_uint(_v) >> 19], 1u);      \
  } while (0)
  for (long long i = gtid; i < n4; i += 2 * NT) {
    float4 pa = p4[i], ta = t4[i];
    long long i2 = i + NT;
    bool h2 = (i2 < n4);
    float4 pb, tb;
    if (h2) { pb = p4[i2]; tb = t4[i2]; }
    PROC1(pa.x, ta.x); PROC1(pa.y, ta.y); PROC1(pa.z, ta.z); PROC1(pa.w, ta.w);
    if (h2) {
      PROC1(pb.x, tb.x); PROC1(pb.y, tb.y); PROC1(pb.z, tb.z); PROC1(pb.w, tb.w);
    }
  }
  for (long long e = (n4 << 2) + gtid; e < n; e += NT) PROC1(preds[e], gts[e]);
#undef PROC1

  double dI = fI, dSp = fSp, dSt = fSt;
#pragma unroll
  for (int off = 32; off; off >>= 1) {
    dI += __shfl_down(dI, off, 64);
    dSp += __shfl_down(dSp, off, 64);
    dSt += __shfl_down(dSt, off, 64);
  }
  if ((t & 63) == 0) {
    int w = t >> 6;
    wred[w][0] = dI; wred[w][1] = dSp; wred[w][2] = dSt;
  }
  __syncthreads();
  if (t == 0) {
    double a = 0, b = 0, c = 0;
#pragma unroll
    for (int w = 0; w < 4; ++w) { a += wred[w][0]; b += wred[w][1]; c += wred[w][2]; }
    blockSums[blockIdx.x * 3 + 0] = a;
    blockSums[blockIdx.x * 3 + 1] = b;
    blockSums[blockIdx.x * 3 + 2] = c;
  }

  unsigned int* dst = hist1R + (size_t)(blockIdx.x & (NREP1 - 1)) * NBINS;
  for (int i = t; i < NBINS; i += 256) {
    unsigned c2 = h[i];
    if (c2) atomicAdd(&dst[i], c2);
  }

  // ---- last-block select1 ----
  __threadfence();  // release: blockSums store + hist flush globally visible
  __syncthreads();
  if (t == 0) lastFlag = (atomicAdd(done1, 1u) == G1 - 1) ? 1u : 0u;
  __syncthreads();
  if (lastFlag) {
    __threadfence();  // acquire: invalidate caches, see all blocks' flushes
    unsigned loc[16];
    unsigned tot = 0;
#pragma unroll
    for (int q = 0; q < 4; ++q) {
      uint4 acc = {0u, 0u, 0u, 0u};
      for (int r = 0; r < NREP1; ++r) {
        uint4 v = *(const uint4*)&hist1R[(size_t)r * NBINS + t * 16 + q * 4];
        acc.x += v.x; acc.y += v.y; acc.z += v.z; acc.w += v.w;
      }
      loc[q * 4 + 0] = acc.x; loc[q * 4 + 1] = acc.y;
      loc[q * 4 + 2] = acc.z; loc[q * 4 + 3] = acc.w;
      tot += acc.x + acc.y + acc.z + acc.w;
    }
    chunk[t] = tot;
    __syncthreads();
    for (int off = 1; off < 256; off <<= 1) {  // suffix scan
      unsigned add = (t + off < 256) ? chunk[t + off] : 0u;
      __syncthreads();
      chunk[t] += add;
      __syncthreads();
    }
    unsigned cum = (t < 255) ? chunk[t + 1] : 0u;
    for (int j = 15; j >= 0; --j) {
      unsigned nc = cum + loc[j];
      if (cum < K && nc >= K) {  // exactly one (t,j) globally satisfies this
        ctl->b1 = (unsigned)(t * 16 + j);
        ctl->r = K - cum;
      }
      cum = nc;
    }
  }
}

// ---------------- pass 2: sum>b1 + refine in b1 (+sel2fin in last block) ----
__global__ void __launch_bounds__(256, 6) pass2_kernel(
    const float* __restrict__ preds, const float* __restrict__ gts,
    long long n, unsigned int K, const Ctl* __restrict__ ctl,
    const double* __restrict__ blockSums, double* __restrict__ blockSgt,
    unsigned int* __restrict__ hist2R, float* __restrict__ sum2R,
    unsigned int* __restrict__ done2, float* __restrict__ out) {
  __shared__ unsigned int hp[NBINS / 2];  // u16-packed fine counts (8KB)
  __shared__ float s[NBINS];              // fine f32 sums (16KB)
  __shared__ unsigned int chunk[256];
  __shared__ double wred[4];
  __shared__ double redsA[4], redsB[4], redsC[4];
  __shared__ double wfin[4][4];
  __shared__ unsigned int sb2, sr2, lastFlag;
  const int t = threadIdx.x;

  for (int i = t; i < NBINS / 2; i += 256) hp[i] = 0u;
  for (int i = t; i < NBINS; i += 256) s[i] = 0.f;
  __syncthreads();
  const unsigned b1v = ctl->b1;  // uniform scalar (written by pass1 last block)

  double sgt = 0.0;
  const long long n4 = n >> 2;
  const float4* p4 = (const float4*)preds;
  const float4* t4 = (const float4*)gts;
  const long long NT = (long long)G2 * 256;
  const long long gtid = (long long)blockIdx.x * 256 + t;

#define PROC2(pp, tt)                                        \
  do {                                                       \
    float _v = poly1_val((pp), (tt));                        \
    unsigned _u = __float_as_uint(_v);                       \
    unsigned _b = _u >> 19;                                  \
    if (_b > b1v) {                                          \
      sgt += (double)_v;                                     \
    } else if (_b == b1v) {                                  \
      unsigned _k = (_u >> 7) & 0xFFFu;                      \
      atomicAdd(&hp[_k >> 1], (_k & 1u) ? 0x10000u : 1u);    \
      atomicAdd(&s[_k], _v);                                 \
    }                                                        \
  } while (0)
  for (long long i = gtid; i < n4; i += 2 * NT) {
    float4 pa = p4[i], ta = t4[i];
    long long i2 = i + NT;
    bool h2 = (i2 < n4);
    float4 pb, tb;
    if (h2) { pb = p4[i2]; tb = t4[i2]; }
    PROC2(pa.x, ta.x); PROC2(pa.y, ta.y); PROC2(pa.z, ta.z); PROC2(pa.w, ta.w);
    if (h2) {
      PROC2(pb.x, tb.x); PROC2(pb.y, tb.y); PROC2(pb.z, tb.z); PROC2(pb.w, tb.w);
    }
  }
  for (long long e = (n4 << 2) + gtid; e < n; e += NT) PROC2(preds[e], gts[e]);
#undef PROC2

#pragma unroll
  for (int off = 32; off; off >>= 1) sgt += __shfl_down(sgt, off, 64);
  if ((t & 63) == 0) wred[t >> 6] = sgt;
  __syncthreads();
  if (t == 0) blockSgt[blockIdx.x] = wred[0] + wred[1] + wred[2] + wred[3];

  unsigned int* hd = hist2R + (size_t)(blockIdx.x & (NREP2 - 1)) * NBINS;
  float* sd = sum2R + (size_t)(blockIdx.x & (NREP2 - 1)) * NBINS;
  for (int i = t; i < NBINS / 2; i += 256) {
    unsigned pw = hp[i];
    unsigned c0 = pw & 0xFFFFu, c1 = pw >> 16;
    if (c0) atomicAdd(&hd[2 * i + 0], c0);
    if (c1) atomicAdd(&hd[2 * i + 1], c1);
  }
  for (int i = t; i < NBINS; i += 256) {
    float sv = s[i];
    if (sv != 0.f) atomicAdd(&sd[i], sv);
  }

  // ---- last-block select2 + finalize ----
  __threadfence();  // release: blockSgt store + replica flush visible
  __syncthreads();
  if (t == 0) lastFlag = (atomicAdd(done2, 1u) == G2 - 1) ? 1u : 0u;
  __syncthreads();
  if (!lastFlag) return;
  __threadfence();  // acquire

  const unsigned K2 = ctl->r;  // remaining count needed from bucket b1 (>= 1)
  unsigned hl[16];
  float sl[16];
  {
    unsigned tot = 0;
#pragma unroll
    for (int q = 0; q < 4; ++q) {
      uint4 ha = {0u, 0u, 0u, 0u};
      float4 sa = {0.f, 0.f, 0.f, 0.f};
      for (int r = 0; r < NREP2; ++r) {
        uint4 hv = *(const uint4*)&hist2R[(size_t)r * NBINS + t * 16 + q * 4];
        float4 sv = *(const float4*)&sum2R[(size_t)r * NBINS + t * 16 + q * 4];
        ha.x += hv.x; ha.y += hv.y; ha.z += hv.z; ha.w += hv.w;
        sa.x += sv.x; sa.y += sv.y; sa.z += sv.z; sa.w += sv.w;
      }
      hl[q * 4 + 0] = ha.x; hl[q * 4 + 1] = ha.y;
      hl[q * 4 + 2] = ha.z; hl[q * 4 + 3] = ha.w;
      sl[q * 4 + 0] = sa.x; sl[q * 4 + 1] = sa.y;
      sl[q * 4 + 2] = sa.z; sl[q * 4 + 3] = sa.w;
      tot += ha.x + ha.y + ha.z + ha.w;
    }
    chunk[t] = tot;
    __syncthreads();
    for (int off = 1; off < 256; off <<= 1) {
      unsigned add = (t + off < 256) ? chunk[t + off] : 0u;
      __syncthreads();
      chunk[t] += add;
      __syncthreads();
    }
    unsigned cum = (t < 255) ? chunk[t + 1] : 0u;
    for (int j = 15; j >= 0; --j) {
      unsigned nc = cum + hl[j];
      if (cum < K2 && nc >= K2) { sb2 = (unsigned)(t * 16 + j); sr2 = K2 - cum; }
      cum = nc;
    }
    __syncthreads();
  }
  const unsigned b2 = sb2, r2 = sr2;

  // exact sum of sub-buckets strictly above b2; b2's own count/sum
  double loc = 0.0, b2s = 0.0, b2c = 0.0;
#pragma unroll
  for (int j = 0; j < 16; ++j) {
    int bin = t * 16 + j;
    if (bin > (int)b2) loc += (double)sl[j];
    if (bin == (int)b2) { b2s = (double)sl[j]; b2c = (double)hl[j]; }
  }
#pragma unroll
  for (int off = 32; off; off >>= 1) {
    loc += __shfl_down(loc, off, 64);
    b2s += __shfl_down(b2s, off, 64);
    b2c += __shfl_down(b2c, off, 64);
  }
  if ((t & 63) == 0) { int w = t >> 6; redsA[w] = loc; redsB[w] = b2s; redsC[w] = b2c; }

  // finalize: reduce per-block dice partials (cross-kernel) + Sgt (this kernel)
  double I = 0, Sp = 0, St = 0, Sg = 0;
  for (int i = t; i < G1; i += 256) {
    I += blockSums[i * 3 + 0];
    Sp += blockSums[i * 3 + 1];
    St += blockSums[i * 3 + 2];
  }
  for (int i = t; i < G2; i += 256) Sg += blockSgt[i];
#pragma unroll
  for (int off = 32; off; off >>= 1) {
    I += __shfl_down(I, off, 64);
    Sp += __shfl_down(Sp, off, 64);
    St += __shfl_down(St, off, 64);
    Sg += __shfl_down(Sg, off, 64);
  }
  if ((t & 63) == 0) {
    int w = t >> 6;
    wfin[w][0] = I; wfin[w][1] = Sp; wfin[w][2] = St; wfin[w][3] = Sg;
  }
  __syncthreads();
  if (t == 0) {
    double S2 = 0, bs = 0, bc = 0, tI = 0, tSp = 0, tSt = 0, tSg = 0;
#pragma unroll
    for (int w = 0; w < 4; ++w) {
      S2 += redsA[w]; bs += redsB[w]; bc += redsC[w];
      tI += wfin[w][0]; tSp += wfin[w][1]; tSt += wfin[w][2]; tSg += wfin[w][3];
    }
    // ties in sub-bucket b2 span < 128 ulps: bin average for the r2 remaining
    double topk_extra = S2 + (double)r2 * (bs / bc);
    double dice = 1.0 - (2.0 * tI + 1.0) / (tSp + tSt + 1.0);
    out[0] = (float)(dice + (tSg + topk_extra) / (double)K);
  }
}

extern "C" void kernel_launch(void* const* d_in, const int* in_sizes, int n_in,
                              void* d_out, int out_size, void* d_ws,
                              size_t ws_size, hipStream_t stream) {
  (void)n_in; (void)out_size; (void)ws_size;
  const float* preds = (const float*)d_in[0];
  const float* gts = (const float*)d_in[1];
  long long n = (long long)in_sizes[0];
  unsigned int K = (unsigned int)(n * 10 / 100);  // matches int(N*10/100)

  char* ws = (char*)d_ws;
  Ctl* ctl = (Ctl*)ws;                                 // @0, 64B
  double* blockSums = (double*)(ws + 64);              // G1*3*8 = 49152 -> 49216
  double* blockSgt = (double*)(ws + 49216);            // G2*8 = 12288 -> 61504
  unsigned int* done1 = (unsigned int*)(ws + 61504);   // counters, 64B pad
  unsigned int* done2 = done1 + 1;
  unsigned int* hist1R = (unsigned int*)(ws + 61568);  // NREP1*NBINS*4 = 131072
  unsigned int* hist2R = (unsigned int*)(ws + 192640); // NREP2*NBINS*4 = 65536
  float* sum2R = (float*)(ws + 258176);                // 65536 -> end 323712

  // zero counters + replica region (contiguous)
  (void)hipMemsetAsync(ws + 61504, 0, 262208, stream);

  pass1_kernel<<<G1, 256, 0, stream>>>(preds, gts, n, K, blockSums, hist1R,
                                       done1, ctl);
  pass2_kernel<<<G2, 256, 0, stream>>>(preds, gts, n, K, ctl, blockSums,
                                       blockSgt, hist2R, sum2R, done2,
                                       (float*)d_out);
}

// Round 4
// 207.779 us; speedup vs baseline: 2.8907x; 2.8907x over previous
//
#include <hip/hip_runtime.h>

// DicepolyTopk: dice loss + mean of top-10% poly1-BCE values over N=16.7M fp32.
// R8: revert R7's last-block-done pattern (device-scope fence + 2048
// same-address atomics serialized chip-wide -> pass1 340us; the R4 journal
// already measured ~39ns per same-address atomic). Back to the proven
// 5-dispatch skeleton: memset -> pass1 -> select1 -> pass2 -> sel2fin.
// Budget arithmetic across R0/R6/R7 shows pass1 ~= 135us (dominant kernel,
// never in top-5 view) vs pass2 48; only structural difference is the
// per-element LDS histogram atomicAdd (SQ_LDS_BANK_CONFLICT 1.86M vs 4.1K).
// -> R8 attacks LDS same-address RMW serialization:
//  - pass1 histogram: 2 lane-parity replicas x 2048 u32 words, u16-packed
//    (two bins/word) = same 16KB LDS; same-bin dupes halved; cross-replica
//    aliases are 2-way same-bank (free, m136). Per-block counts <= 8192 so
//    u16 halves cannot overflow. Halves merged at flush.
//  - both passes: 16 elems/iter (4 dense float4 per array at strides
//    0..3*NT) -> 128B/thread of loads in flight.
//  - select1 restored as its own 1-block dispatch (R6's per-block embedding
//    cost ~5-8us inside pass2); sel2fin reads ctl->r directly.

#define NBINS 4096
#define NREP1 8
#define NREP2 4
#define G1 2048
#define G2 2048
#define POLY_EPS 3.1f
#define LN2F 0.69314718056f

struct Ctl {
  unsigned int b1;  // L1 bucket containing the k-th largest value
  unsigned int r;   // k - count(strictly greater L1 buckets)
};

// bce in log2 domain: a2=log2(p), b2=log2(1-p); bce2 = -(b2 + t*(a2-b2))
// bce = bce2*ln2 ; pt = 2^(-bce2) ; poly1 = bce + (1-pt)*eps, clamped >= 0.
__device__ __forceinline__ float poly1_val(float p, float t) {
  float a2 = __builtin_amdgcn_logf(p);         // v_log_f32: log2(p)
  float b2 = __builtin_amdgcn_logf(1.0f - p);  // log2(1-p)
  float bce2 = -(b2 + t * (a2 - b2));
  float pt = __builtin_amdgcn_exp2f(-bce2);    // v_exp_f32: 2^(-bce2)
  float v = bce2 * LN2F + (1.0f - pt) * POLY_EPS;
  return v > 0.0f ? v : 0.0f;
}

// ---------------- pass 1: dice sums + L1 histogram -------------------------
__global__ void __launch_bounds__(256) pass1_kernel(
    const float* __restrict__ preds, const float* __restrict__ gts,
    long long n, double* __restrict__ blockSums,
    unsigned int* __restrict__ hist1R) {
  // 2 replicas (lane parity) x 2048 words; word = replica*2048 + (bin>>1),
  // halfword = bin&1. 16KB total.
  __shared__ unsigned int hp[NBINS];
  __shared__ double wred[4][3];
  const int t = threadIdx.x;
  for (int i = t; i < NBINS; i += 256) hp[i] = 0u;
  __syncthreads();
  const unsigned rep = (unsigned)(t & 1) << 11;  // 0 or 2048

  float fI = 0.f, fSp = 0.f, fSt = 0.f;
  const long long n4 = n >> 2;
  const float4* p4 = (const float4*)preds;
  const float4* t4 = (const float4*)gts;
  const long long NT = (long long)G1 * 256;
  const long long gtid = (long long)blockIdx.x * 256 + t;

#define PROC1(pp, tt)                                          \
  do {                                                         \
    float _p = (pp), _t = (tt);                                \
    fI += _p * _t;                                             \
    fSp += _p;                                                 \
    fSt += _t;                                                 \
    float _v = poly1_val(_p, _t);                              \
    unsigned _b = __float_as_uint(_v) >> 19;                   \
    atomicAdd(&hp[rep + (_b >> 1)], (_b & 1u) ? 0x10000u : 1u);\
  } while (0)
#define PROC1V(P, T) \
  do { PROC1(P.x, T.x); PROC1(P.y, T.y); PROC1(P.z, T.z); PROC1(P.w, T.w); } while (0)

  for (long long i = gtid; i < n4; i += 4 * NT) {
    long long i1 = i + NT, i2 = i + 2 * NT, i3 = i + 3 * NT;
    bool g1 = i1 < n4, g2 = i2 < n4, g3 = i3 < n4;
    float4 P0 = p4[i], T0 = t4[i];
    float4 P1, T1, P2, T2, P3, T3;
    if (g1) { P1 = p4[i1]; T1 = t4[i1]; }
    if (g2) { P2 = p4[i2]; T2 = t4[i2]; }
    if (g3) { P3 = p4[i3]; T3 = t4[i3]; }
    PROC1V(P0, T0);
    if (g1) PROC1V(P1, T1);
    if (g2) PROC1V(P2, T2);
    if (g3) PROC1V(P3, T3);
  }
  for (long long e = (n4 << 2) + gtid; e < n; e += NT) PROC1(preds[e], gts[e]);
#undef PROC1V
#undef PROC1

  double dI = fI, dSp = fSp, dSt = fSt;
#pragma unroll
  for (int off = 32; off; off >>= 1) {
    dI += __shfl_down(dI, off, 64);
    dSp += __shfl_down(dSp, off, 64);
    dSt += __shfl_down(dSt, off, 64);
  }
  if ((t & 63) == 0) {
    int w = t >> 6;
    wred[w][0] = dI; wred[w][1] = dSp; wred[w][2] = dSt;
  }
  __syncthreads();
  if (t == 0) {
    double a = 0, b = 0, c = 0;
#pragma unroll
    for (int w = 0; w < 4; ++w) { a += wred[w][0]; b += wred[w][1]; c += wred[w][2]; }
    blockSums[blockIdx.x * 3 + 0] = a;
    blockSums[blockIdx.x * 3 + 1] = b;
    blockSums[blockIdx.x * 3 + 2] = c;
  }

  // merge replicas+halves, flush to one of NREP1 global replica histograms
  unsigned int* dst = hist1R + (size_t)(blockIdx.x & (NREP1 - 1)) * NBINS;
  for (int i = t; i < 2048; i += 256) {
    unsigned a = hp[i], b = hp[i + 2048];
    unsigned c0 = (a & 0xFFFFu) + (b & 0xFFFFu);
    unsigned c1 = (a >> 16) + (b >> 16);
    if (c0) atomicAdd(&dst[2 * i + 0], c0);
    if (c1) atomicAdd(&dst[2 * i + 1], c1);
  }
}

// ---------------- select1: find L1 bucket of the k-th value ----------------
__global__ void __launch_bounds__(1024) select1_kernel(
    Ctl* ctl, const unsigned int* __restrict__ hist1R, unsigned int K) {
  __shared__ unsigned int chunk[1024];
  int t = threadIdx.x;
  unsigned hl[4];
  unsigned c = 0;
  {
    uint4 acc = {0u, 0u, 0u, 0u};
    for (int r = 0; r < NREP1; ++r) {
      uint4 v = *(const uint4*)&hist1R[(size_t)r * NBINS + t * 4];
      acc.x += v.x; acc.y += v.y; acc.z += v.z; acc.w += v.w;
    }
    hl[0] = acc.x; hl[1] = acc.y; hl[2] = acc.z; hl[3] = acc.w;
    c = acc.x + acc.y + acc.z + acc.w;
  }
  chunk[t] = c;
  __syncthreads();
  for (int off = 1; off < 1024; off <<= 1) {  // suffix scan
    unsigned add = (t + off < 1024) ? chunk[t + off] : 0u;
    __syncthreads();
    chunk[t] += add;
    __syncthreads();
  }
  unsigned cum = (t < 1023) ? chunk[t + 1] : 0u;
  for (int j = 3; j >= 0; --j) {
    unsigned nc = cum + hl[j];
    if (cum < K && nc >= K) {  // exactly one (t,j) globally satisfies this
      ctl->b1 = (unsigned)(t * 4 + j);
      ctl->r = K - cum;
    }
    cum = nc;
  }
}

// ---------------- pass 2: sum above b1 + refine within b1 ------------------
__global__ void __launch_bounds__(256) pass2_kernel(
    const float* __restrict__ preds, const float* __restrict__ gts,
    long long n, const Ctl* __restrict__ ctl, double* __restrict__ blockSgt,
    unsigned int* __restrict__ hist2R, float* __restrict__ sum2R) {
  __shared__ unsigned int hp[NBINS / 2];  // u16-packed fine counts (8KB)
  __shared__ float s[NBINS];              // fine f32 sums (16KB)
  __shared__ double wred[4];
  const int t = threadIdx.x;

  for (int i = t; i < NBINS / 2; i += 256) hp[i] = 0u;
  for (int i = t; i < NBINS; i += 256) s[i] = 0.f;
  __syncthreads();
  const unsigned b1v = ctl->b1;

  double sgt = 0.0;
  const long long n4 = n >> 2;
  const float4* p4 = (const float4*)preds;
  const float4* t4 = (const float4*)gts;
  const long long NT = (long long)G2 * 256;
  const long long gtid = (long long)blockIdx.x * 256 + t;

#define PROC2(pp, tt)                                        \
  do {                                                       \
    float _v = poly1_val((pp), (tt));                        \
    unsigned _u = __float_as_uint(_v);                       \
    unsigned _b = _u >> 19;                                  \
    if (_b > b1v) {                                          \
      sgt += (double)_v;                                     \
    } else if (_b == b1v) {                                  \
      unsigned _k = (_u >> 7) & 0xFFFu;                      \
      atomicAdd(&hp[_k >> 1], (_k & 1u) ? 0x10000u : 1u);    \
      atomicAdd(&s[_k], _v);                                 \
    }                                                        \
  } while (0)
#define PROC2V(P, T) \
  do { PROC2(P.x, T.x); PROC2(P.y, T.y); PROC2(P.z, T.z); PROC2(P.w, T.w); } while (0)

  for (long long i = gtid; i < n4; i += 4 * NT) {
    long long i1 = i + NT, i2 = i + 2 * NT, i3 = i + 3 * NT;
    bool g1 = i1 < n4, g2 = i2 < n4, g3 = i3 < n4;
    float4 P0 = p4[i], T0 = t4[i];
    float4 P1, T1, P2, T2, P3, T3;
    if (g1) { P1 = p4[i1]; T1 = t4[i1]; }
    if (g2) { P2 = p4[i2]; T2 = t4[i2]; }
    if (g3) { P3 = p4[i3]; T3 = t4[i3]; }
    PROC2V(P0, T0);
    if (g1) PROC2V(P1, T1);
    if (g2) PROC2V(P2, T2);
    if (g3) PROC2V(P3, T3);
  }
  for (long long e = (n4 << 2) + gtid; e < n; e += NT) PROC2(preds[e], gts[e]);
#undef PROC2V
#undef PROC2

#pragma unroll
  for (int off = 32; off; off >>= 1) sgt += __shfl_down(sgt, off, 64);
  if ((t & 63) == 0) wred[t >> 6] = sgt;
  __syncthreads();
  if (t == 0) blockSgt[blockIdx.x] = wred[0] + wred[1] + wred[2] + wred[3];

  unsigned int* hd = hist2R + (size_t)(blockIdx.x & (NREP2 - 1)) * NBINS;
  float* sd = sum2R + (size_t)(blockIdx.x & (NREP2 - 1)) * NBINS;
  for (int i = t; i < NBINS / 2; i += 256) {
    unsigned pw = hp[i];
    unsigned c0 = pw & 0xFFFFu, c1 = pw >> 16;
    if (c0) atomicAdd(&hd[2 * i + 0], c0);
    if (c1) atomicAdd(&hd[2 * i + 1], c1);
  }
  for (int i = t; i < NBINS; i += 256) {
    float sv = s[i];
    if (sv != 0.f) atomicAdd(&sd[i], sv);
  }
}

// ---------------- select2 + finalize: one block ----------------------------
__global__ void __launch_bounds__(1024) sel2fin_kernel(
    const Ctl* __restrict__ ctl, const unsigned int* __restrict__ hist2R,
    const float* __restrict__ sum2R, const double* __restrict__ blockSums,
    const double* __restrict__ blockSgt, float* __restrict__ out,
    unsigned int K) {
  __shared__ unsigned int chunk[1024];
  __shared__ double redsA[16], redsB[16], redsC[16];
  __shared__ double wfin[16][4];
  __shared__ unsigned int sb2, sr2;
  const int t = threadIdx.x;
  const unsigned K2 = ctl->r;  // remaining count needed from bucket b1 (>= 1)

  // ---- select2 within bucket b1 (fine bins t*4..t*4+3) ----
  unsigned hl[4];
  float sl[4];
  {
    uint4 hacc = {0u, 0u, 0u, 0u};
    float4 sacc = {0.f, 0.f, 0.f, 0.f};
    for (int r = 0; r < NREP2; ++r) {
      uint4 hv = *(const uint4*)&hist2R[(size_t)r * NBINS + t * 4];
      float4 sv = *(const float4*)&sum2R[(size_t)r * NBINS + t * 4];
      hacc.x += hv.x; hacc.y += hv.y; hacc.z += hv.z; hacc.w += hv.w;
      sacc.x += sv.x; sacc.y += sv.y; sacc.z += sv.z; sacc.w += sv.w;
    }
    hl[0] = hacc.x; hl[1] = hacc.y; hl[2] = hacc.z; hl[3] = hacc.w;
    sl[0] = sacc.x; sl[1] = sacc.y; sl[2] = sacc.z; sl[3] = sacc.w;
    chunk[t] = hacc.x + hacc.y + hacc.z + hacc.w;
  }
  __syncthreads();
  for (int off = 1; off < 1024; off <<= 1) {
    unsigned add = (t + off < 1024) ? chunk[t + off] : 0u;
    __syncthreads();
    chunk[t] += add;
    __syncthreads();
  }
  unsigned cum = (t < 1023) ? chunk[t + 1] : 0u;
  for (int j = 3; j >= 0; --j) {
    unsigned nc = cum + hl[j];
    if (cum < K2 && nc >= K2) { sb2 = (unsigned)(t * 4 + j); sr2 = K2 - cum; }
    cum = nc;
  }
  __syncthreads();
  const unsigned b2 = sb2, r2 = sr2;

  // exact sum of sub-buckets strictly above b2; b2's own count/sum
  double loc = 0.0, b2s = 0.0, b2c = 0.0;
#pragma unroll
  for (int j = 0; j < 4; ++j) {
    int bin = t * 4 + j;
    if (bin > (int)b2) loc += (double)sl[j];
    if (bin == (int)b2) { b2s = (double)sl[j]; b2c = (double)hl[j]; }
  }
#pragma unroll
  for (int off = 32; off; off >>= 1) {
    loc += __shfl_down(loc, off, 64);
    b2s += __shfl_down(b2s, off, 64);
    b2c += __shfl_down(b2c, off, 64);
  }
  if ((t & 63) == 0) { int w = t >> 6; redsA[w] = loc; redsB[w] = b2s; redsC[w] = b2c; }

  // ---- finalize: reduce per-block dice partials + Sgt ----
  double I = 0, Sp = 0, St = 0, Sg = 0;
  for (int i = t; i < G1; i += 1024) {
    I += blockSums[i * 3 + 0];
    Sp += blockSums[i * 3 + 1];
    St += blockSums[i * 3 + 2];
  }
  for (int i = t; i < G2; i += 1024) Sg += blockSgt[i];
#pragma unroll
  for (int off = 32; off; off >>= 1) {
    I += __shfl_down(I, off, 64);
    Sp += __shfl_down(Sp, off, 64);
    St += __shfl_down(St, off, 64);
    Sg += __shfl_down(Sg, off, 64);
  }
  if ((t & 63) == 0) {
    int w = t >> 6;
    wfin[w][0] = I; wfin[w][1] = Sp; wfin[w][2] = St; wfin[w][3] = Sg;
  }
  __syncthreads();
  if (t == 0) {
    double S2 = 0, bs = 0, bc = 0, tI = 0, tSp = 0, tSt = 0, tSg = 0;
#pragma unroll
    for (int w = 0; w < 16; ++w) {
      S2 += redsA[w]; bs += redsB[w]; bc += redsC[w];
      tI += wfin[w][0]; tSp += wfin[w][1]; tSt += wfin[w][2]; tSg += wfin[w][3];
    }
    // ties in sub-bucket b2 span < 128 ulps: bin average for the r2 remaining
    double topk_extra = S2 + (double)r2 * (bs / bc);
    double dice = 1.0 - (2.0 * tI + 1.0) / (tSp + tSt + 1.0);
    out[0] = (float)(dice + (tSg + topk_extra) / (double)K);
  }
}

extern "C" void kernel_launch(void* const* d_in, const int* in_sizes, int n_in,
                              void* d_out, int out_size, void* d_ws,
                              size_t ws_size, hipStream_t stream) {
  (void)n_in; (void)out_size; (void)ws_size;
  const float* preds = (const float*)d_in[0];
  const float* gts = (const float*)d_in[1];
  long long n = (long long)in_sizes[0];
  unsigned int K = (unsigned int)(n * 10 / 100);  // matches int(N*10/100)

  char* ws = (char*)d_ws;
  Ctl* ctl = (Ctl*)ws;                                 // @0, 64B
  double* blockSums = (double*)(ws + 64);              // G1*3*8 = 49152 -> 49216
  double* blockSgt = (double*)(ws + 49216);            // G2*8 = 16384 -> 65600
  unsigned int* hist1R = (unsigned int*)(ws + 65600);  // NREP1*NBINS*4 = 131072
  unsigned int* hist2R = (unsigned int*)(ws + 196672); // NREP2*NBINS*4 = 65536
  float* sum2R = (float*)(ws + 262208);                // 65536 -> end 327744

  // zero only the atomic-accumulated replica region (contiguous, 256KB)
  (void)hipMemsetAsync(ws + 65600, 0, 262144, stream);

  pass1_kernel<<<G1, 256, 0, stream>>>(preds, gts, n, blockSums, hist1R);
  select1_kernel<<<1, 1024, 0, stream>>>(ctl, hist1R, K);
  pass2_kernel<<<G2, 256, 0, stream>>>(preds, gts, n, ctl, blockSgt, hist2R,
                                       sum2R);
  sel2fin_kernel<<<1, 1024, 0, stream>>>(ctl, hist2R, sum2R, blockSums,
                                         blockSgt, (float*)d_out, K);
}